// Round 10
// baseline (6096.105 us; speedup 1.0000x reference)
//
#include <hip/hip_runtime.h>
#include <hip/hip_fp16.h>

#define T_STEPS 512
#define NB      64
#define NI      128
#define NH      256
#define LK      16
#define RS      32
#define NS      (LK + RS)

// ws layout (bytes)
#define WP_OFF   0            // uint4[192*256]: gate weights, k-pairs packed as 4 half2 (f,i,o,g)
#define VAP8_OFF 786432       // uint4[32*256]: Va^T, 8 consecutive k per entry, per output h
#define UAP8_OFF 917504       // uint4[32*256]: Ua^T, same layout
#define GX_OFF   5242880      // fp16 uint2[512*64*256]: precomputed x-part of gates (f,i,o,g)
#define WS_NEED  (GX_OFF + (size_t)T_STEPS * NB * NH * 8)

typedef _Float16 half2v __attribute__((ext_vector_type(2)));

__device__ __forceinline__ float hdot(unsigned int w, unsigned int s, float c) {
    return __builtin_amdgcn_fdot2(__builtin_bit_cast(half2v, w),
                                  __builtin_bit_cast(half2v, s), c, false);
}

__device__ __forceinline__ float fsig(float x) {
    return __builtin_amdgcn_rcpf(1.0f + __expf(-x));
}
__device__ __forceinline__ float ftanh(float x) {
    x = fminf(15.0f, fmaxf(-15.0f, x));
    float e = __expf(2.0f * x);
    return (e - 1.0f) * __builtin_amdgcn_rcpf(e + 1.0f);
}

__global__ void prep_weights(const float* __restrict__ Wf, const float* __restrict__ Wi,
                             const float* __restrict__ Wo, const float* __restrict__ Wg,
                             const float* __restrict__ Ua, const float* __restrict__ Va,
                             unsigned char* __restrict__ ws) {
    int e = blockIdx.x * 256 + threadIdx.x;   // 0..65535
    if (e < 49152) {                          // WP: e = k2*256 + h
        int h = e & 255, k2 = e >> 8, k = 2 * k2;
        uint4 w; __half2 t;
        t = __floats2half2_rn(Wf[h * 384 + k], Wf[h * 384 + k + 1]); w.x = *(unsigned int*)&t;
        t = __floats2half2_rn(Wi[h * 384 + k], Wi[h * 384 + k + 1]); w.y = *(unsigned int*)&t;
        t = __floats2half2_rn(Wo[h * 384 + k], Wo[h * 384 + k + 1]); w.z = *(unsigned int*)&t;
        t = __floats2half2_rn(Wg[h * 384 + k], Wg[h * 384 + k + 1]); w.w = *(unsigned int*)&t;
        ((uint4*)(ws + WP_OFF))[e] = w;
    } else {                                  // Va/Ua 8-k packs
        int e2 = e - 49152;                   // 0..16383
        const float* S = (e2 < 8192) ? Va : Ua;
        int e3 = e2 & 8191;
        int h = e3 & 255, j = e3 >> 8, k = 8 * j;
        uint4 w; __half2 t;
        t = __floats2half2_rn(S[h * 256 + k + 0], S[h * 256 + k + 1]); w.x = *(unsigned int*)&t;
        t = __floats2half2_rn(S[h * 256 + k + 2], S[h * 256 + k + 3]); w.y = *(unsigned int*)&t;
        t = __floats2half2_rn(S[h * 256 + k + 4], S[h * 256 + k + 5]); w.z = *(unsigned int*)&t;
        t = __floats2half2_rn(S[h * 256 + k + 6], S[h * 256 + k + 7]); w.w = *(unsigned int*)&t;
        ((uint4*)(ws + VAP8_OFF))[e2] = w;
    }
}

// Parallel GEMM: gate_x[t][b][h][4g] = W_x @ x_t
__global__ __launch_bounds__(256) void gx_gemm(const float* __restrict__ x,
                                               unsigned char* __restrict__ ws) {
    const int t = blockIdx.x, bg = blockIdx.y, tid = threadIdx.x;
    const uint4* __restrict__ WP = (const uint4*)(ws + WP_OFF);
    uint2* __restrict__ GX = (uint2*)(ws + GX_OFF);
    __shared__ float s_xx[16 * 128];
    const float* xb = x + ((size_t)t * NB + bg * 16) * NI;
#pragma unroll
    for (int r = 0; r < 8; ++r) s_xx[tid + 256 * r] = xb[tid + 256 * r];
    __syncthreads();
    const int h = tid;
    float acc[16][4];
#pragma unroll
    for (int bb = 0; bb < 16; ++bb) { acc[bb][0] = acc[bb][1] = acc[bb][2] = acc[bb][3] = 0.f; }
    for (int k2 = 128; k2 < 192; ++k2) {
        uint4 w = WP[k2 * NH + h];
        float2 wf = __half22float2(*(const __half2*)&w.x);
        float2 wi = __half22float2(*(const __half2*)&w.y);
        float2 wo = __half22float2(*(const __half2*)&w.z);
        float2 wg = __half22float2(*(const __half2*)&w.w);
        int kk = 2 * k2 - 256;
#pragma unroll
        for (int bb = 0; bb < 16; ++bb) {
            float2 xv = *(const float2*)(s_xx + bb * 128 + kk);
            acc[bb][0] += wf.x * xv.x + wf.y * xv.y;
            acc[bb][1] += wi.x * xv.x + wi.y * xv.y;
            acc[bb][2] += wo.x * xv.x + wo.y * xv.y;
            acc[bb][3] += wg.x * xv.x + wg.y * xv.y;
        }
    }
#pragma unroll
    for (int bb = 0; bb < 16; ++bb) {
        __half2 p0 = __floats2half2_rn(acc[bb][0], acc[bb][1]);
        __half2 p1 = __floats2half2_rn(acc[bb][2], acc[bb][3]);
        uint2 u; u.x = *(unsigned int*)&p0; u.y = *(unsigned int*)&p1;
        GX[((size_t)t * NB + bg * 16 + bb) * NH + h] = u;
    }
}

// ======================= linearized kernel =======================
// W@st = 0.5*(W@h_{t-1} + sum_n alpha_n * W@comb[n]) -- exact by linearity.
// Rings of f16 projections (WG@h, Va@h, Ua@h) replace raw memory; eviction is a copy.
// Per step: [A: waves 0-11 stream WG/Va@h_{t-1} (640KB) || B: wave 12 attention+softmax
// +bookkeeping (needs only q_{t-1} and Ua ring, complete since D2(t-1))] | C: 48-slot
// weighted sums (gates_pre, q_next) + evictee reg reads | D1: activations + evict
// writes | D2: Ua@h_t (128KB) into ring. 4 barriers/step; attention hides under stream.
__global__ __launch_bounds__(1024, 1) void rel_lstm_lin(
    const float* __restrict__ bf_g, const float* __restrict__ bi_g,
    const float* __restrict__ bo_g, const float* __restrict__ bg_g,
    const float* __restrict__ vv_g,
    unsigned char* __restrict__ ws, float* __restrict__ out) {
    const int tid = threadIdx.x;
    const int b   = blockIdx.x;
    const int wv  = tid >> 6;
    const int ln  = tid & 63;

    const uint4* __restrict__ WP   = (const uint4*)(ws + WP_OFF);
    const uint4* __restrict__ VaP8 = (const uint4*)(ws + VAP8_OFF);
    const uint4* __restrict__ UaP8 = (const uint4*)(ws + UAP8_OFF);
    const uint2* __restrict__ GX   = (const uint2*)(ws + GX_OFF);

    __shared__ __align__(16) _Float16 WG_ring[48][1024];  // out = g*256+h; rows 0-15 short ring, 16-47 long
    __shared__ __align__(16) _Float16 Va_ring[48][256];
    __shared__ __align__(16) _Float16 Ua_ring[48][264];   // +8 pad (bank spread for es reads)
    __shared__ __align__(16) float s_gp[1024];            // gates_pre (4 gates x 256 h)
    __shared__ __align__(16) _Float16 s_hid_h[NH];        // h_{t-1} (f16)
    __shared__ __align__(16) float s_q[NH];               // q_t = Va@st_{t-1}
    __shared__ __align__(16) float s_v[NH];
    __shared__ float s_al[NS];
    __shared__ float s_scores[T_STEPS];
    __shared__ float s_buck[RS];
    __shared__ int s_fill, s_upd, s_pos;

    unsigned int* WG32 = (unsigned int*)&WG_ring[0][0];   // row stride 512 dwords
    unsigned int* VA32 = (unsigned int*)&Va_ring[0][0];   // row stride 128 dwords
    unsigned int* UA32 = (unsigned int*)&Ua_ring[0][0];   // row stride 132 dwords

    // ---- init ----
    for (int i = tid; i < 48 * 512; i += 1024) WG32[i] = 0u;
    for (int i = tid; i < 48 * 128; i += 1024) VA32[i] = 0u;
    for (int i = tid; i < 48 * 132; i += 1024) UA32[i] = 0u;
    if (tid < T_STEPS) s_scores[tid] = 0.f;
    if (tid < NH) { s_v[tid] = vv_g[tid]; s_q[tid] = 0.f; }
    if (tid < 128) ((unsigned int*)s_hid_h)[tid] = 0u;
    if (tid < NS) s_al[tid] = 0.f;
    if (tid < RS) s_buck[tid] = 0.f;
    if (tid == 0) { s_fill = 0; s_upd = 0; s_pos = 0; }
    float bfv = 0.f, biv = 0.f, bov = 0.f, bgv = 0.f;
    if (tid < NH) { bfv = bf_g[tid]; biv = bi_g[tid]; bov = bo_g[tid]; bgv = bg_g[tid]; }
    float ct = 0.f;
    int base = 0;
    __syncthreads();

    for (int t = 0; t < T_STEPS; ++t) {
        uint2 gx = {0u, 0u};
        if (tid < NH) gx = GX[((size_t)t * NB + b) * NH + tid];   // L2 latency hides under A
        unsigned int evW = 0u, evV = 0u, evU = 0u;
        if (t > 0) {
            const int nslot = (base + LK - 1) & (LK - 1);         // slot of h_{t-1}
            // ========== A (waves 0-11, weight stream) || B (wave 12, attention) ==========
            if (wv < 8) {                 // WG@h_{t-1}: h=(wv<<5)|(ln&31), k-half=ln>>5
                const int h = (wv << 5) | (ln & 31);
                const int kh = ln >> 5;
                const unsigned int* H2 = (const unsigned int*)s_hid_h;
                float af = 0.f, ai = 0.f, ao = 0.f, ag = 0.f;
#pragma unroll 8
                for (int k2 = kh * 64; k2 < kh * 64 + 64; ++k2) {
                    uint4 w = WP[(k2 << 8) + h];
                    unsigned int s2 = H2[k2];                     // broadcast
                    af = hdot(w.x, s2, af); ai = hdot(w.y, s2, ai);
                    ao = hdot(w.z, s2, ao); ag = hdot(w.w, s2, ag);
                }
                af += __shfl_xor(af, 32); ai += __shfl_xor(ai, 32);
                ao += __shfl_xor(ao, 32); ag += __shfl_xor(ag, 32);
                if (kh == 0) {
                    _Float16* row = WG_ring[nslot];
                    row[h]       = (_Float16)af;
                    row[256 + h] = (_Float16)ai;
                    row[512 + h] = (_Float16)ao;
                    row[768 + h] = (_Float16)ag;
                }
            } else if (wv < 12) {         // Va@h_{t-1}: h=(wv-8)*64+ln, full k
                const int h = ((wv - 8) << 6) | ln;
                const uint4* H4 = (const uint4*)s_hid_h;
                float acc = 0.f;
#pragma unroll 8
                for (int j = 0; j < 32; ++j) {
                    uint4 w = VaP8[(j << 8) + h];
                    uint4 s = H4[j];
                    acc = hdot(w.x, s.x, acc); acc = hdot(w.y, s.y, acc);
                    acc = hdot(w.z, s.z, acc); acc = hdot(w.w, s.w, acc);
                }
                Va_ring[nslot][h] = (_Float16)acc;
            } else if (wv == 12) {        // B: es (3 batches x 16 rows x 4 lanes x 64 h)
                const int s4 = ln & 3;
                float e[3];
#pragma unroll
                for (int m = 0; m < 3; ++m) {
                    int row = m * 16 + (ln >> 2);
                    bool skip; const _Float16* ua;
                    if (row < LK) { skip = row < LK - t; ua = Ua_ring[(base + row) & (LK - 1)]; }
                    else          { skip = (row - LK) >= s_fill; ua = Ua_ring[row]; }
                    float p = -1e30f;
                    if (!skip) {
                        p = 0.f;
#pragma unroll
                        for (int q = 0; q < 16; ++q) {
                            int h0 = s4 * 4 + q * 16;
                            float4 q4 = *(const float4*)(s_q + h0);
                            float4 v4 = *(const float4*)(s_v + h0);
                            uint2 uh = *(const uint2*)(ua + h0);
                            float2 a0 = __half22float2(*(const __half2*)&uh.x);
                            float2 a1 = __half22float2(*(const __half2*)&uh.y);
                            p += v4.x * ftanh(q4.x + a0.x) + v4.y * ftanh(q4.y + a0.y)
                               + v4.z * ftanh(q4.z + a1.x) + v4.w * ftanh(q4.w + a1.y);
                        }
                        p += __shfl_xor(p, 1, 4);
                        p += __shfl_xor(p, 2, 4);
                    }
                    e[m] = p;
                }
                int src = (ln & 15) << 2;                 // lane holding row (ln&15) of each batch
                float f0 = __shfl(e[0], src), f1 = __shfl(e[1], src), f2 = __shfl(e[2], src);
                float ee = (ln < 16) ? f0 : (ln < 32) ? f1 : (ln < 48) ? f2 : -1e30f;
                float mm = ee;
#pragma unroll
                for (int off = 32; off; off >>= 1) mm = fmaxf(mm, __shfl_xor(mm, off));
                float a = (ln < NS) ? __expf(ee - mm) : 0.f;
                float ssum = a;
#pragma unroll
                for (int off = 32; off; off >>= 1) ssum += __shfl_xor(ssum, off);
                float al = a * __builtin_amdgcn_rcpf(ssum);
                if (ln < NS) s_al[ln] = al;
                // first-min argmin over s_buck (reads precede lane0's update in wave order)
                float bv = (ln < RS) ? s_buck[ln] : 1e30f;
                int   bi2 = (ln < RS) ? ln : 999;
#pragma unroll
                for (int off = 1; off < 32; off <<= 1) {
                    float v2 = __shfl_xor(bv, off, 32);
                    int   i2 = __shfl_xor(bi2, off, 32);
                    if (v2 < bv || (v2 == bv && i2 < bi2)) { bv = v2; bi2 = i2; }
                }
                float cs = 0.f;
                if (ln < LK) {
                    int time = t - LK + ln;
                    if (time >= 0) { float ns = s_scores[time] + al; s_scores[time] = ns; cs = ns; }
                }
                if (ln == 0) {
                    int upd = 0, pos = 0;
                    if (t >= LK) {
                        int fill = s_fill;
                        bool full = fill >= RS;
                        upd = (!full) || (cs > bv);
                        pos = full ? bi2 : fill;
                        if (upd) { s_buck[pos] = cs; if (!full) s_fill = fill + 1; }
                    }
                    s_upd = upd; s_pos = pos;
                }
            }
            __syncthreads();
            // ========== C: weighted sums over 48 slots + evictee register reads ==========
            {
                const int eslot = base & (LK - 1);                // slot of h_{t-16}
                if (tid < 512) {                                  // gates_pre dword tid
                    float a0 = 0.f, a1 = 0.f;
#pragma unroll
                    for (int n = 0; n < NS; ++n) {
                        int slot = (n < LK) ? ((base + n) & (LK - 1)) : n;
                        float c = s_al[n] + ((n == LK - 1) ? 1.0f : 0.0f);  // +1: mem[-1] term
                        unsigned int u = WG32[slot * 512 + tid];
                        float2 f = __half22float2(*(const __half2*)&u);
                        a0 += c * f.x; a1 += c * f.y;
                    }
                    s_gp[2 * tid]     = 0.5f * a0;
                    s_gp[2 * tid + 1] = 0.5f * a1;
                    evW = WG32[eslot * 512 + tid];
                } else if (tid < 640) {                           // q_next dword tid-512
                    const int d = tid - 512;
                    float a0 = 0.f, a1 = 0.f;
#pragma unroll
                    for (int n = 0; n < NS; ++n) {
                        int slot = (n < LK) ? ((base + n) & (LK - 1)) : n;
                        float c = s_al[n] + ((n == LK - 1) ? 1.0f : 0.0f);
                        unsigned int u = VA32[slot * 128 + d];
                        float2 f = __half22float2(*(const __half2*)&u);
                        a0 += c * f.x; a1 += c * f.y;
                    }
                    s_q[2 * d]     = 0.5f * a0;
                    s_q[2 * d + 1] = 0.5f * a1;
                    evV = VA32[eslot * 128 + d];
                } else if (tid < 768) {
                    evU = UA32[eslot * 132 + (tid - 640)];
                }
            }
            __syncthreads();
        }
        // ========== D1: gates + activations + hid; eviction writes ==========
        if (tid < NH) {
            float pf = bfv, pi = biv, po = bov, pg = bgv;
            if (t > 0) {
                pf += s_gp[tid];       pi += s_gp[256 + tid];
                po += s_gp[512 + tid]; pg += s_gp[768 + tid];
            }
            float2 fi = __half22float2(*(const __half2*)&gx.x);
            float2 og = __half22float2(*(const __half2*)&gx.y);
            pf += fi.x; pi += fi.y; po += og.x; pg += og.y;
            float f  = fsig(pf);
            float ii = fsig(pi);
            float o  = fsig(po);
            float g  = ftanh(pg);
            ct = f * ct + ii * g;                 // t=0: ct=0 -> matches reference
            float hid = o * ftanh(ct);
            out[((size_t)t * NB + b) * NH + tid] = hid;
            s_hid_h[tid] = (_Float16)hid;
        }
        if (t > 0 && s_upd) {                     // evict h_{t-16} projections -> long slot
            const int lrow = LK + s_pos;
            if (tid < 512)      WG32[lrow * 512 + tid] = evW;
            else if (tid < 640) VA32[lrow * 128 + (tid - 512)] = evV;
            else if (tid < 768) UA32[lrow * 132 + (tid - 640)] = evU;
        }
        __syncthreads();
        // ========== D2: Ua@h_t into ring slot base&15 (needed by B(t+1)) ==========
        {
            const int h = (wv << 4) | (ln & 15);
            const int kc = ln >> 4;
            const uint4* H4 = (const uint4*)s_hid_h;
            float acc = 0.f;
#pragma unroll
            for (int j = 0; j < 8; ++j) {
                int jj = kc * 8 + j;
                uint4 w = UaP8[(jj << 8) + h];
                uint4 s = H4[jj];
                acc = hdot(w.x, s.x, acc); acc = hdot(w.y, s.y, acc);
                acc = hdot(w.z, s.z, acc); acc = hdot(w.w, s.w, acc);
            }
            acc += __shfl_xor(acc, 16); acc += __shfl_xor(acc, 32);
            if (kc == 0) Ua_ring[base & (LK - 1)][h] = (_Float16)acc;
        }
        base++;
        __syncthreads();
    }
}

// ===================== mono kernel (R2-proven), fallback for small ws =====================
__global__ __launch_bounds__(1024, 1) void rel_lstm_mono(
    const float* __restrict__ x,
    const float* __restrict__ bf_g, const float* __restrict__ bi_g,
    const float* __restrict__ bo_g, const float* __restrict__ bg_g,
    const float* __restrict__ vv_g,
    unsigned char* __restrict__ ws, float* __restrict__ out) {
    const int tid = threadIdx.x;
    const int b   = blockIdx.x;
    const int wv  = tid >> 6;
    const int ln  = tid & 63;
    const int h16 = (wv << 4) | (ln & 15);
    const int kc  = ln >> 4;

    const uint4* __restrict__ WP   = (const uint4*)(ws + WP_OFF);
    const uint4* __restrict__ VaP8 = (const uint4*)(ws + VAP8_OFF);
    const uint4* __restrict__ UaP8 = (const uint4*)(ws + UAP8_OFF);

    __shared__ __align__(16) _Float16 s_in_h[NH + NI];
    __shared__ __align__(16) _Float16 s_hid_h[NH];
    __shared__ __align__(16) float s_q[NH];
    __shared__ __align__(16) float s_v[NH];
    __shared__ __align__(16) float s_mem[LK][NH];
    __shared__ __align__(16) float s_memua[LK][NH + 8];
    __shared__ __align__(16) float s_lraw[RS * NH];
    __shared__ __align__(16) float s_lua[RS * NH];
    __shared__ float s_es[NS], s_al[NS];
    __shared__ float s_scores[T_STEPS];
    __shared__ float s_mask[RS], s_buck[RS];
    __shared__ float s_minv;
    __shared__ int s_minp, s_fill, s_upd, s_pos;

    for (int i = tid; i < LK * NH; i += 1024) ((float*)s_mem)[i] = 0.f;
    for (int i = tid; i < LK * (NH + 8); i += 1024) ((float*)s_memua)[i] = 0.f;
    for (int i = tid; i < RS * NH; i += 1024) { s_lraw[i] = 0.f; s_lua[i] = 0.f; }
    if (tid < T_STEPS) s_scores[tid] = 0.f;
    if (tid < NH) s_v[tid] = vv_g[tid];
    if (tid < (NH + NI) / 2) ((unsigned int*)s_in_h)[tid] = 0u;
    if (tid < RS) { s_mask[tid] = -1e30f; s_buck[tid] = 0.f; }
    if (tid == 0) { s_fill = 0; s_upd = 0; s_pos = 0; s_minv = 0.f; s_minp = 0; }
    float bfv = 0.f, biv = 0.f, bov = 0.f, bgv = 0.f;
    if (kc == 0) { bfv = bf_g[h16]; biv = bi_g[h16]; bov = bo_g[h16]; bgv = bg_g[h16]; }
    if (tid < 64) {
        float2 xv = ((const float2*)(x + (size_t)b * NI))[tid];
        __half2 hx = __floats2half2_rn(xv.x, xv.y);
        ((unsigned int*)s_in_h)[NH / 2 + tid] = *(unsigned int*)&hx;
    }
    float ct = 0.f;
    int base = 0;
    __syncthreads();

    for (int t = 0; t < T_STEPS; ++t) {
        float evA = 0.f, evB = 0.f;
        if (t > 0) {
            {
                const uint4* P   = (wv < 8) ? VaP8 : UaP8;
                const uint4* SRC = (wv < 8) ? (const uint4*)s_in_h : (const uint4*)s_hid_h;
                const int hh = ((wv & 7) << 5) | (ln & 31);
                const int ch = ln >> 5;
                float acc = 0.f;
#pragma unroll
                for (int jj = 0; jj < 16; ++jj) {
                    int j = (ch << 4) | jj;
                    uint4 w = P[(j << 8) + hh];
                    uint4 s = SRC[j];
                    acc = hdot(w.x, s.x, acc);
                    acc = hdot(w.y, s.y, acc);
                    acc = hdot(w.z, s.z, acc);
                    acc = hdot(w.w, s.w, acc);
                }
                acc += __shfl_xor(acc, 32, 64);
                if (ch == 0) {
                    if (wv < 8) s_q[hh] = acc;
                    else        s_memua[(base + LK - 1) & (LK - 1)][hh] = acc;
                }
                if (kc == 1) {
                    int p0 = base & (LK - 1);
                    evA = s_mem[p0][h16];
                    evB = s_memua[p0][h16];
                }
                if (tid < 64) {
                    float2 xv = ((const float2*)(x + ((size_t)t * NB + b) * NI))[tid];
                    __half2 hx = __floats2half2_rn(xv.x, xv.y);
                    ((unsigned int*)s_in_h)[NH / 2 + tid] = *(unsigned int*)&hx;
                }
            }
            __syncthreads();
            if (tid < 768) {
                const int row = tid >> 4, l = tid & 15;
                bool skip;
                const float* ua;
                if (row < LK) { skip = row < LK - t; ua = s_memua[(base + row) & (LK - 1)]; }
                else          { skip = s_mask[row - LK] < -1e29f; ua = s_lua + (row - LK) * NH; }
                float esv = -1e30f;
                if (!skip) {
                    float p = 0.f;
#pragma unroll
                    for (int jj = 0; jj < 4; ++jj) {
                        int hh = (l << 2) + (jj << 6);
                        float4 q4 = *(const float4*)(s_q + hh);
                        float4 v4 = *(const float4*)(s_v + hh);
                        float4 u4 = *(const float4*)(ua + hh);
                        p += v4.x * ftanh(q4.x + u4.x);
                        p += v4.y * ftanh(q4.y + u4.y);
                        p += v4.z * ftanh(q4.z + u4.z);
                        p += v4.w * ftanh(q4.w + u4.w);
                    }
                    p += __shfl_xor(p, 1, 16);
                    p += __shfl_xor(p, 2, 16);
                    p += __shfl_xor(p, 4, 16);
                    p += __shfl_xor(p, 8, 16);
                    esv = p;
                }
                if (l == 0) s_es[row] = esv;
            } else if (tid >= 960 && tid < 992) {
                int l = tid - 960;
                float v = s_buck[l]; int idx = l;
#pragma unroll
                for (int off = 1; off < 32; off <<= 1) {
                    float v2 = __shfl_xor(v, off, 32);
                    int  i2 = __shfl_xor(idx, off, 32);
                    if (v2 < v || (v2 == v && i2 < idx)) { v = v2; idx = i2; }
                }
                if (l == 0) { s_minv = v; s_minp = idx; }
            }
            __syncthreads();
            if (tid < 64) {
                float e = (tid < NS) ? s_es[tid] : -1e30f;
                float m = e;
#pragma unroll
                for (int off = 32; off; off >>= 1) m = fmaxf(m, __shfl_xor(m, off, 64));
                float a = (tid < NS) ? __expf(e - m) : 0.f;
                float ssum = a;
#pragma unroll
                for (int off = 32; off; off >>= 1) ssum += __shfl_xor(ssum, off, 64);
                float al = a * __builtin_amdgcn_rcpf(ssum);
                if (tid < NS) s_al[tid] = al;
                float cs = 0.f;
                if (tid < LK) {
                    int time = t - LK + tid;
                    if (time >= 0) {
                        float ns = s_scores[time] + al;
                        s_scores[time] = ns;
                        cs = ns;
                    }
                }
                if (tid == 0) {
                    int upd = 0, pos = 0;
                    if (t >= LK) {
                        int fill = s_fill;
                        bool full = fill >= RS;
                        upd = (!full) || (cs > s_minv);
                        pos = full ? s_minp : fill;
                        if (upd) { s_mask[pos] = 0.f; s_buck[pos] = cs; if (!full) s_fill = fill + 1; }
                    }
                    s_upd = upd; s_pos = pos;
                }
            }
            __syncthreads();
            {
                float catt = 0.f;
                const int n0 = kc * 12;
#pragma unroll
                for (int n = n0; n < n0 + 12; ++n) {
                    float a = s_al[n];
                    if (n < LK) catt += a * s_mem[(base + n) & (LK - 1)][h16];
                    else if (a != 0.f) catt += a * s_lraw[(n - LK) * NH + h16];
                }
                catt += __shfl_xor(catt, 16, 64);
                catt += __shfl_xor(catt, 32, 64);
                if (kc == 0) {
                    float stv = 0.5f * (s_mem[(base + LK - 1) & (LK - 1)][h16] + catt);
                    s_in_h[h16] = (_Float16)stv;
                }
            }
            __syncthreads();
        }
        {
            const unsigned int* S2 = (const unsigned int*)s_in_h;
            float af = 0.f, ai = 0.f, ao = 0.f, ag = 0.f;
            const int lo = kc * 48;
#pragma unroll 8
            for (int k2 = lo; k2 < lo + 48; ++k2) {
                uint4 w = WP[(k2 << 8) + h16];
                unsigned int s2 = S2[k2];
                af = hdot(w.x, s2, af);
                ai = hdot(w.y, s2, ai);
                ao = hdot(w.z, s2, ao);
                ag = hdot(w.w, s2, ag);
            }
            af += __shfl_xor(af, 16, 64); af += __shfl_xor(af, 32, 64);
            ai += __shfl_xor(ai, 16, 64); ai += __shfl_xor(ai, 32, 64);
            ao += __shfl_xor(ao, 16, 64); ao += __shfl_xor(ao, 32, 64);
            ag += __shfl_xor(ag, 16, 64); ag += __shfl_xor(ag, 32, 64);
            if (kc == 0) {
                float f  = fsig(af + bfv);
                float ii = fsig(ai + biv);
                float o  = fsig(ao + bov);
                float g  = ftanh(ag + bgv);
                ct = f * ct + ii * g;
                float hid = o * ftanh(ct);
                out[((size_t)t * NB + b) * NH + h16] = hid;
                s_mem[base & (LK - 1)][h16] = hid;
                s_hid_h[h16] = (_Float16)hid;
            } else if (kc == 1 && s_upd) {
                s_lraw[s_pos * NH + h16] = evA;
                s_lua[s_pos * NH + h16]  = evB;
            }
        }
        base++;
        __syncthreads();
    }
}

extern "C" void kernel_launch(void* const* d_in, const int* in_sizes, int n_in,
                              void* d_out, int out_size, void* d_ws, size_t ws_size,
                              hipStream_t stream) {
    const float* x  = (const float*)d_in[0];
    const float* Wf = (const float*)d_in[1];
    const float* bf = (const float*)d_in[2];
    const float* Wi = (const float*)d_in[3];
    const float* bi = (const float*)d_in[4];
    const float* Wo = (const float*)d_in[5];
    const float* bo = (const float*)d_in[6];
    const float* Wg = (const float*)d_in[7];
    const float* bg = (const float*)d_in[8];
    const float* Ua = (const float*)d_in[9];
    const float* Va = (const float*)d_in[10];
    const float* vv = (const float*)d_in[11];
    unsigned char* ws = (unsigned char*)d_ws;
    float* out = (float*)d_out;

    prep_weights<<<256, 256, 0, stream>>>(Wf, Wi, Wo, Wg, Ua, Va, ws);
    if (ws_size >= WS_NEED) {
        gx_gemm<<<dim3(T_STEPS, 4), 256, 0, stream>>>(x, ws);
        rel_lstm_lin<<<NB, 1024, 0, stream>>>(bf, bi, bo, bg, vv, ws, out);
    } else {
        rel_lstm_mono<<<NB, 1024, 0, stream>>>(x, bf, bi, bo, bg, vv, ws, out);
    }
}